// Round 8
// baseline (370.851 us; speedup 1.0000x reference)
//
#include <hip/hip_runtime.h>

#define NPTS 100000
#define PB 64                         // points per block
#define NBLK ((NPTS + PB - 1) / PB)   // 1563
#define INF 1280
#define PSTR 544                      // sF per-point stride (512 + 32 pad)

using short8 = __attribute__((ext_vector_type(8))) short;
using f32x4  = __attribute__((ext_vector_type(4))) float;

__device__ __forceinline__ unsigned short f2bf(float x) {
  unsigned u = __float_as_uint(x);
  return (unsigned short)((u + 0x7FFFu + ((u >> 16) & 1u)) >> 16);  // RNE
}
__device__ __forceinline__ unsigned pack2(float a, float b) {
  return (unsigned)f2bf(a) | ((unsigned)f2bf(b) << 16);
}

// ---- prep: in_f f32 -> bf16 (12.8 MB, L3-resident for gathers) ----
__global__ void k_prep(const float* __restrict__ in_f, unsigned short* __restrict__ inbf) {
  int i = blockIdx.x * 256 + threadIdx.x;
  if (i < 1600000) {
    float4 v = ((const float4*)in_f)[i];
    ushort4 o;
    o.x = f2bf(v.x); o.y = f2bf(v.y); o.z = f2bf(v.z); o.w = f2bf(v.w);
    ((ushort4*)inbf)[i] = o;
  }
}

// ---- retile linear_weights -> bf16 B-fragment order (R2-verified) ----
__global__ void k_wconv(const float* __restrict__ W, unsigned short* __restrict__ Wb) {
  int g = blockIdx.x * 256 + threadIdx.x;   // 0..327679
  int j = g & 7;
  int col = (g >> 3) & 15;
  int ks = (g >> 7) & 31;
  int rest = g >> 12;
  int ct = rest % 5, nt = rest / 5;
  int kh = ks * 8 + j;
  int m = kh >> 4, ci = kh & 15;
  Wb[g] = f2bf(W[(nt * 16 + col) * INF + (ct * 16 + ci) * 16 + m]);
}

// ---- fused kernel ----
// Thread owns staging unit (p, h, kq): point p (wave-private, p = w*8+lane>>3),
// channel half h (8 ch), neighbor quad kq (k = 4kq..4kq+3).
// sF[p][x16][k16] bf16 (PSTR pad); sA[p][k^256] in A-frag order (528B rows).
__global__ __launch_bounds__(512, 3) void k_fused(
    const unsigned short* __restrict__ inbf, const int* __restrict__ nbr,
    const float* __restrict__ wn_g, const float* __restrict__ add_f,
    const unsigned short* __restrict__ Wb, const float* __restrict__ bias,
    float* __restrict__ out)
{
  __shared__ __align__(16) unsigned char sF[PB * PSTR];  // 34816 B
  __shared__ __align__(16) unsigned char sA[PB * 528];   // 33792 B

  const int t = threadIdx.x;
  const int w = t >> 6, lane = t & 63;
  const int g16 = lane >> 4, c16 = lane & 15;
  const long p0 = (long)blockIdx.x * PB;

  // staging unit: p-local, h, kq
  const int upl = w * 8 + (lane >> 3);         // point, wave-private
  const int uh  = (lane >> 2) & 1;
  const int ukq = lane & 3;
  long upp = p0 + upl; if (upp >= NPTS) upp = NPTS - 1;
  const int4 uidx = *(const int4*)&nbr[upp * 16 + ukq * 4];  // 4 neighbor ids
  unsigned char* const ubase = sF + upl * PSTR + uh * 256 + ukq * 8;

  unsigned g[4][4];                            // 4 gathered 16B granules
  auto gload = [&](int ct) {
#pragma unroll
    for (int j = 0; j < 4; ++j) {
      int idx = ((const int*)&uidx)[j];
      *(uint4*)&g[j][0] = *(const uint4*)(inbf + (long)idx * 64 + ct * 16 + uh * 8);
    }
  };
  auto swrite_g = [&]() {                      // perm-pack + 8 ds_write_b64
#pragma unroll
    for (int x = 0; x < 8; ++x) {
      int wi = x >> 1;
      unsigned sel = (x & 1) ? 0x07060302u : 0x05040100u;
      unsigned d0 = __builtin_amdgcn_perm(g[1][wi], g[0][wi], sel);
      unsigned d1 = __builtin_amdgcn_perm(g[3][wi], g[2][wi], sel);
      *(uint2*)(ubase + x * 32) = make_uint2(d0, d1);
    }
  };
  float4 fr[8];                                // f32 staging (wn / add_f)
  auto fload = [&](const float* __restrict__ src) {  // src[(pp*16+k)*16 + m]
#pragma unroll
    for (int j = 0; j < 4; ++j) {
      const float* s = src + (upp * 16 + ukq * 4 + j) * 16 + uh * 8;
      fr[j * 2]     = *(const float4*)s;
      fr[j * 2 + 1] = *(const float4*)(s + 4);
    }
  };
  auto swrite_f = [&]() {
#pragma unroll
    for (int x = 0; x < 8; ++x) {
      int fi = x >> 2, xe = x & 3;
      unsigned d0 = pack2(((const float*)&fr[0 + fi])[xe], ((const float*)&fr[2 + fi])[xe]);
      unsigned d1 = pack2(((const float*)&fr[4 + fi])[xe], ((const float*)&fr[6 + fi])[xe]);
      *(uint2*)(ubase + x * 32) = make_uint2(d0, d1);
    }
  };

  // ---- prologue: issue gather(0), stage wn, preload bfr, stage feat(0) ----
  gload(0);
  fload(wn_g);
  swrite_f();          // wn -> own sF rows

  short8 bfr[8];       // wn B-frags for this wave's 8 points
#pragma unroll
  for (int i = 0; i < 8; ++i) {
    bfr[i] = (short8){0, 0, 0, 0, 0, 0, 0, 0};
    if (g16 < 2)
      bfr[i] = *(const short8*)(sF + (w * 8 + i) * PSTR + c16 * 32 + g16 * 16);
  }
  asm volatile("s_waitcnt lgkmcnt(0)" ::: "memory");  // bfr done before overwrite
  swrite_g();          // feat(0) -> own sF rows

  auto pconv = [&]() {                   // per wave: 8 own points, 1 MFMA each
    short8 af[8];
#pragma unroll
    for (int i = 0; i < 8; ++i) {
      af[i] = (short8){0, 0, 0, 0, 0, 0, 0, 0};
      if (g16 < 2)
        af[i] = *(const short8*)(sF + (w * 8 + i) * PSTR + c16 * 32 + g16 * 16);
    }
#pragma unroll
    for (int i = 0; i < 8; ++i) {
      int p = w * 8 + i;
      f32x4 d = __builtin_amdgcn_mfma_f32_16x16x32_bf16(
          af[i], bfr[i], (f32x4){0.f, 0.f, 0.f, 0.f}, 0, 0, 0);
      // D: row(c)=g16*4+r, col(m)=c16; k^=m*16+c -> byte c16*32+g16*8+r*2
      *(uint2*)(sA + p * 528 + c16 * 32 + g16 * 8) =
          make_uint2(pack2(d[0], d[1]), pack2(d[2], d[3]));
    }
  };

  f32x4 acc[2][4];
#pragma unroll
  for (int rr = 0; rr < 2; ++rr)
#pragma unroll
    for (int ntl = 0; ntl < 4; ++ntl) acc[rr][ntl] = (f32x4){0.f, 0.f, 0.f, 0.f};

  const int rt0 = (w & 1) * 2;         // 2 row-tiles
  const int nt0 = (w >> 1) * 4;        // 4 col-tiles

  auto gemm = [&](int ct) {
#pragma unroll
    for (int h2 = 0; h2 < 4; ++h2) {   // kl pair per step
      short8 bb[2][4];
#pragma unroll
      for (int kk = 0; kk < 2; ++kk)
#pragma unroll
        for (int ntl = 0; ntl < 4; ++ntl) {
          int nt = nt0 + ntl, kl = h2 * 2 + kk;
          bb[kk][ntl] = *(const short8*)(Wb + ((long)((nt * 5 + ct) * 32 + kl * 4 + g16) * 16 + c16) * 8);
        }
      short8 aa[2][2];
#pragma unroll
      for (int kk = 0; kk < 2; ++kk)
#pragma unroll
        for (int rr = 0; rr < 2; ++rr)
          aa[kk][rr] = *(const short8*)(sA + ((rt0 + rr) * 16 + c16) * 528 + (h2 * 2 + kk) * 64 + g16 * 16);
#pragma unroll
      for (int kk = 0; kk < 2; ++kk)
#pragma unroll
        for (int ntl = 0; ntl < 4; ++ntl)
#pragma unroll
          for (int rr = 0; rr < 2; ++rr)
            acc[rr][ntl] = __builtin_amdgcn_mfma_f32_16x16x32_bf16(aa[kk][rr], bb[kk][ntl], acc[rr][ntl], 0, 0, 0);
    }
  };

  // ---- main schedule ----
  pconv();             // ct=0 (own sF -> own sA rows)
  __syncthreads();     // sA(0) ready
  for (int ct = 0; ct < 5; ++ct) {
    if (ct < 3) gload(ct + 1);           // issue-early (T14)
    else if (ct == 3) fload(add_f);
    gemm(ct);
    if (ct < 4) {
      if (ct < 3) swrite_g(); else swrite_f();   // own sF rows: no barrier needed
      __syncthreads();                   // all gemm(ct) sA-reads done
      pconv();
      __syncthreads();                   // sA(ct+1) ready
    }
  }

  // ---- epilogue: 4 consecutive 64B segments per row -> full 128B lines ----
  float bv[4];
#pragma unroll
  for (int ntl = 0; ntl < 4; ++ntl) bv[ntl] = bias[(nt0 + ntl) * 16 + c16];
#pragma unroll
  for (int rr = 0; rr < 2; ++rr) {
#pragma unroll
    for (int r = 0; r < 4; ++r) {
      long prow = p0 + (rt0 + rr) * 16 + g16 * 4 + r;
      if (prow < NPTS) {
        float* o = out + prow * 256 + c16;
#pragma unroll
        for (int ntl = 0; ntl < 4; ++ntl)
          o[(nt0 + ntl) * 16] = acc[rr][ntl][r] + bv[ntl];
      }
    }
  }
}

extern "C" void kernel_launch(void* const* d_in, const int* in_sizes, int n_in,
                              void* d_out, int out_size, void* d_ws, size_t ws_size,
                              hipStream_t stream) {
  const float* in_f  = (const float*)d_in[0];
  const int*   nbr   = (const int*)d_in[1];
  const float* wn    = (const float*)d_in[5];
  const float* add_f = (const float*)d_in[6];
  const float* W     = (const float*)d_in[7];
  const float* bias  = (const float*)d_in[8];
  float* out = (float*)d_out;

  unsigned short* inbf = (unsigned short*)d_ws;                       // 12.8 MB
  unsigned short* Wb   = (unsigned short*)((char*)d_ws + 13631488);   // 640 KB

  k_prep<<<dim3(6250), dim3(256), 0, stream>>>(in_f, inbf);
  k_wconv<<<dim3(1280), dim3(256), 0, stream>>>(W, Wb);
  k_fused<<<dim3(NBLK), dim3(512), 0, stream>>>(inbf, nbr, wn, add_f, Wb, bias, out);
}